// Round 1
// baseline (13501.472 us; speedup 1.0000x reference)
//
#include <hip/hip_runtime.h>
#include <stdint.h>

// ---------------- problem constants ----------------
constexpr int Dd   = 1024;
constexpr int NHc  = 16;
constexpr int Ec   = 8;
constexpr int Lc   = 2;
constexpr int HFFc = 4096;
constexpr int Bc   = 8;
constexpr int Tc   = 1024;
constexpr int Nc   = Bc * Tc;        // 8192 tokens
constexpr int CAP  = 17408;          // padded token-expert rows capacity (>= 16384 + 8*127, /128)
constexpr int MAXT = CAP / 128;      // 136 M-tiles for MoE GEMMs

// ---------------- embed ----------------
__global__ __launch_bounds__(256) void embed_kernel(
    const int* __restrict__ ids, const float* __restrict__ emb,
    const float* __restrict__ pos, float* __restrict__ x, float* __restrict__ lb)
{
  int n = blockIdx.x;
  int tid = threadIdx.x;
  int id = ids[n];
  int tpos = n & (Tc - 1);
  size_t o = (size_t)n * Dd + tid * 4;
  float4 e = *(const float4*)(emb + (size_t)id * Dd + tid * 4);
  float4 p = *(const float4*)(pos + (size_t)tpos * Dd + tid * 4);
  float4 r;
  r.x = e.x + p.x; r.y = e.y + p.y; r.z = e.z + p.z; r.w = e.w + p.w;
  *(float4*)(x + o) = r;
  if (n == 0 && tid == 0) lb[0] = 0.0f;
}

// ---------------- fp32 tiled GEMM, 128x128x16, 256 threads ----------------
// MODE 0: C = A@B + bias                       (A direct rows)
// MODE 1: H = relu(A@B + bias[e]), A rows gathered via perm (token = perm>>1)
// MODE 2: moe_out[slot][tok] = wgt*(A@B + bias[e]), A direct rows (A = H)
template<int MODE>
__global__ __launch_bounds__(256)
void gemm_kernel(const float* __restrict__ A, int lda,
                 const float* __restrict__ B, int ldb,
                 const float* __restrict__ bias,
                 float* __restrict__ C, int ldc,
                 int K,
                 const int* __restrict__ tile_e,
                 long long strideB, int strideBias,
                 const int* __restrict__ perm, const float* __restrict__ wgt,
                 float* __restrict__ moe_out)
{
  const int tid = threadIdx.x;
  const int m0 = blockIdx.x * 128;
  const int n0 = blockIdx.y * 128;
  const float* Bp = B;
  const float* biasp = bias;
  if (MODE != 0) {
    int e = tile_e[blockIdx.x];
    if (e < 0) return;
    Bp = B + (size_t)e * (size_t)strideB;
    biasp = bias + (size_t)e * strideBias;
  }

  __shared__ float As[16][132];
  __shared__ float Bs[16][132];

  const int tx = tid & 15;   // col group
  const int ty = tid >> 4;   // row group (0..15)

  float acc[8][8];
#pragma unroll
  for (int i = 0; i < 8; ++i)
#pragma unroll
    for (int j = 0; j < 8; ++j) acc[i][j] = 0.0f;

  // staging indices
  const int am = tid >> 1;          // 0..127
  const int ak = (tid & 1) * 8;     // 0 or 8
  size_t arow_off;
  if (MODE == 1) {
    int pp = perm[m0 + am];
    int tok = (pp < 0) ? 0 : (pp >> 1);
    arow_off = (size_t)tok * lda;
  } else {
    arow_off = (size_t)(m0 + am) * lda;
  }
  const int bk = tid >> 4;          // 0..15
  const int bn = (tid & 15) * 8;    // 0..120

  for (int k0 = 0; k0 < K; k0 += 16) {
    {
      const float* src = A + arow_off + k0 + ak;
      float4 v0 = *(const float4*)(src);
      float4 v1 = *(const float4*)(src + 4);
      As[ak + 0][am] = v0.x; As[ak + 1][am] = v0.y;
      As[ak + 2][am] = v0.z; As[ak + 3][am] = v0.w;
      As[ak + 4][am] = v1.x; As[ak + 5][am] = v1.y;
      As[ak + 6][am] = v1.z; As[ak + 7][am] = v1.w;
    }
    {
      const float* srcb = Bp + (size_t)(k0 + bk) * ldb + n0 + bn;
      float4 w0 = *(const float4*)(srcb);
      float4 w1 = *(const float4*)(srcb + 4);
      *(float4*)&Bs[bk][bn] = w0;
      *(float4*)&Bs[bk][bn + 4] = w1;
    }
    __syncthreads();
#pragma unroll
    for (int kk = 0; kk < 16; ++kk) {
      float4 a0 = *(const float4*)&As[kk][ty * 4];
      float4 a1 = *(const float4*)&As[kk][64 + ty * 4];
      float4 b0 = *(const float4*)&Bs[kk][tx * 4];
      float4 b1 = *(const float4*)&Bs[kk][64 + tx * 4];
      float av[8] = {a0.x, a0.y, a0.z, a0.w, a1.x, a1.y, a1.z, a1.w};
      float bv[8] = {b0.x, b0.y, b0.z, b0.w, b1.x, b1.y, b1.z, b1.w};
#pragma unroll
      for (int i = 0; i < 8; ++i)
#pragma unroll
        for (int j = 0; j < 8; ++j)
          acc[i][j] += av[i] * bv[j];
    }
    __syncthreads();
  }

  // epilogue
  float bias_v[8];
#pragma unroll
  for (int j = 0; j < 8; ++j) {
    int col = (j < 4) ? (tx * 4 + j) : (64 + tx * 4 + (j - 4));
    bias_v[j] = biasp[n0 + col];
  }
#pragma unroll
  for (int i = 0; i < 8; ++i) {
    int rl = (i < 4) ? (ty * 4 + i) : (64 + ty * 4 + (i - 4));
    int grow = m0 + rl;
    if (MODE == 0) {
      float* dst = C + (size_t)grow * ldc + n0;
      float4 o0, o1;
      o0.x = acc[i][0] + bias_v[0]; o0.y = acc[i][1] + bias_v[1];
      o0.z = acc[i][2] + bias_v[2]; o0.w = acc[i][3] + bias_v[3];
      o1.x = acc[i][4] + bias_v[4]; o1.y = acc[i][5] + bias_v[5];
      o1.z = acc[i][6] + bias_v[6]; o1.w = acc[i][7] + bias_v[7];
      *(float4*)(dst + tx * 4) = o0;
      *(float4*)(dst + 64 + tx * 4) = o1;
    } else if (MODE == 1) {
      float* dst = C + (size_t)grow * ldc + n0;
      float4 o0, o1;
      o0.x = fmaxf(acc[i][0] + bias_v[0], 0.0f); o0.y = fmaxf(acc[i][1] + bias_v[1], 0.0f);
      o0.z = fmaxf(acc[i][2] + bias_v[2], 0.0f); o0.w = fmaxf(acc[i][3] + bias_v[3], 0.0f);
      o1.x = fmaxf(acc[i][4] + bias_v[4], 0.0f); o1.y = fmaxf(acc[i][5] + bias_v[5], 0.0f);
      o1.z = fmaxf(acc[i][6] + bias_v[6], 0.0f); o1.w = fmaxf(acc[i][7] + bias_v[7], 0.0f);
      *(float4*)(dst + tx * 4) = o0;
      *(float4*)(dst + 64 + tx * 4) = o1;
    } else {
      int pp = perm[grow];
      if (pp >= 0) {
        float wv = wgt[grow];
        int tok = pp >> 1, slot = pp & 1;
        float* dst = moe_out + ((size_t)slot * Nc + tok) * Dd + n0;
        float4 o0, o1;
        o0.x = (acc[i][0] + bias_v[0]) * wv; o0.y = (acc[i][1] + bias_v[1]) * wv;
        o0.z = (acc[i][2] + bias_v[2]) * wv; o0.w = (acc[i][3] + bias_v[3]) * wv;
        o1.x = (acc[i][4] + bias_v[4]) * wv; o1.y = (acc[i][5] + bias_v[5]) * wv;
        o1.z = (acc[i][6] + bias_v[6]) * wv; o1.w = (acc[i][7] + bias_v[7]) * wv;
        *(float4*)(dst + tx * 4) = o0;
        *(float4*)(dst + 64 + tx * 4) = o1;
      }
    }
  }
}

// ---------------- causal attention: 4 query rows / block, 256 threads ----------------
__global__ __launch_bounds__(256) void attn_kernel(
    const float* __restrict__ qkv, float* __restrict__ out)
{
  int t0 = blockIdx.x * 4;
  int h = blockIdx.y;
  int b = blockIdx.z;
  int tid = threadIdx.x;
  int wave = tid >> 6, lane = tid & 63;
  int t = t0 + wave;

  __shared__ float Kl[64][65];
  __shared__ float Sl[4][1024];
  __shared__ float ql[4][64];

  // load q (scaled by 1/sqrt(dh))
  {
    int w = tid >> 6;
    int d = tid & 63;
    ql[w][d] = qkv[((size_t)(b * Tc + t0 + w)) * 3072 + (h << 6) + d] * 0.125f;
  }
  __syncthreads();

  float qreg[64];
#pragma unroll
  for (int d = 0; d < 64; ++d) qreg[d] = ql[wave][d];

  int nch = (t0 + 3) / 64 + 1;

  // phase 1: scores
  for (int c = 0; c < nch; ++c) {
    int s0 = c * 64;
    {
      int r = tid >> 2, db = (tid & 3) * 16;
      const float* src = qkv + ((size_t)(b * Tc + s0 + r)) * 3072 + Dd + (h << 6) + db;
#pragma unroll
      for (int cc = 0; cc < 4; ++cc) {
        float4 v = *(const float4*)(src + 4 * cc);
        Kl[r][db + 4 * cc + 0] = v.x; Kl[r][db + 4 * cc + 1] = v.y;
        Kl[r][db + 4 * cc + 2] = v.z; Kl[r][db + 4 * cc + 3] = v.w;
      }
    }
    __syncthreads();
    {
      int s = s0 + lane;
      float sc = -1e30f;
      if (s <= t) {
        float a = 0.0f;
#pragma unroll
        for (int d = 0; d < 64; ++d) a += qreg[d] * Kl[lane][d];
        sc = a;
      }
      Sl[wave][s] = sc;
    }
    __syncthreads();
  }

  // softmax (per wave, full row)
  float m = -1e30f;
  for (int s = lane; s < nch * 64; s += 64) m = fmaxf(m, Sl[wave][s]);
  for (int off = 32; off; off >>= 1) m = fmaxf(m, __shfl_xor(m, off));
  float sum = 0.0f;
  for (int s = lane; s < nch * 64; s += 64) {
    float p = expf(Sl[wave][s] - m);
    Sl[wave][s] = p;
    sum += p;
  }
  for (int off = 32; off; off >>= 1) sum += __shfl_xor(sum, off);
  float inv = 1.0f / sum;
  __syncthreads();

  // phase 2: PV
  float o = 0.0f;
  for (int c = 0; c < nch; ++c) {
    int s0 = c * 64;
    {
      int r = tid >> 2, db = (tid & 3) * 16;
      const float* src = qkv + ((size_t)(b * Tc + s0 + r)) * 3072 + 2 * Dd + (h << 6) + db;
#pragma unroll
      for (int cc = 0; cc < 4; ++cc) {
        float4 v = *(const float4*)(src + 4 * cc);
        Kl[r][db + 4 * cc + 0] = v.x; Kl[r][db + 4 * cc + 1] = v.y;
        Kl[r][db + 4 * cc + 2] = v.z; Kl[r][db + 4 * cc + 3] = v.w;
      }
    }
    __syncthreads();
    int lim = t - s0 + 1;
    if (lim > 64) lim = 64;
    if (lim < 0) lim = 0;
    for (int i = 0; i < lim; ++i) o += Sl[wave][s0 + i] * Kl[i][lane];
    __syncthreads();
  }
  out[((size_t)(b * Tc + t)) * Dd + (h << 6) + lane] = o * inv;
}

// ---------------- LayerNorm (x + add1 [+ add2]) ----------------
__global__ __launch_bounds__(256) void ln_kernel(
    const float* __restrict__ xin, const float* __restrict__ add1,
    const float* __restrict__ add2, const float* __restrict__ g,
    const float* __restrict__ bt, float* __restrict__ xout)
{
  int row = blockIdx.x;
  int tid = threadIdx.x;
  size_t base = (size_t)row * Dd + tid * 4;
  float4 v = *(const float4*)(xin + base);
  float4 a = *(const float4*)(add1 + base);
  v.x += a.x; v.y += a.y; v.z += a.z; v.w += a.w;
  if (add2) {
    float4 a2 = *(const float4*)(add2 + base);
    v.x += a2.x; v.y += a2.y; v.z += a2.z; v.w += a2.w;
  }
  float s = v.x + v.y + v.z + v.w;
  float q = v.x * v.x + v.y * v.y + v.z * v.z + v.w * v.w;
  for (int off = 32; off; off >>= 1) {
    s += __shfl_xor(s, off);
    q += __shfl_xor(q, off);
  }
  __shared__ float red[4][2];
  int wave = tid >> 6, lane = tid & 63;
  if (lane == 0) { red[wave][0] = s; red[wave][1] = q; }
  __syncthreads();
  s = red[0][0] + red[1][0] + red[2][0] + red[3][0];
  q = red[0][1] + red[1][1] + red[2][1] + red[3][1];
  float mean = s * (1.0f / Dd);
  float var = q * (1.0f / Dd) - mean * mean;
  float rsig = 1.0f / sqrtf(var + 1e-5f);
  float4 gg = *(const float4*)(g + tid * 4);
  float4 bb = *(const float4*)(bt + tid * 4);
  float4 ov;
  ov.x = (v.x - mean) * rsig * gg.x + bb.x;
  ov.y = (v.y - mean) * rsig * gg.y + bb.y;
  ov.z = (v.z - mean) * rsig * gg.z + bb.z;
  ov.w = (v.w - mean) * rsig * gg.w + bb.w;
  *(float4*)(xout + base) = ov;
}

// ---------------- routing init ----------------
__global__ __launch_bounds__(256) void initroute_kernel(
    int* __restrict__ perm, int* __restrict__ cnt, int* __restrict__ fill,
    float* __restrict__ Psum)
{
  int i = blockIdx.x * 256 + threadIdx.x;
  if (i < CAP) perm[i] = -1;
  if (blockIdx.x == 0 && threadIdx.x < Ec) {
    cnt[threadIdx.x] = 0;
    fill[threadIdx.x] = 0;
    Psum[threadIdx.x] = 0.0f;
  }
}

// ---------------- router: one wave per token ----------------
__global__ __launch_bounds__(64) void route_kernel(
    const float* __restrict__ x, const float* __restrict__ gW,
    const float* __restrict__ gb,
    int* __restrict__ e0a, int* __restrict__ e1a,
    float* __restrict__ w0a, float* __restrict__ w1a,
    int* __restrict__ cnt, float* __restrict__ Psum)
{
  int n = blockIdx.x;
  int lane = threadIdx.x;
  const float* xr = x + (size_t)n * Dd;
  float a[8] = {0, 0, 0, 0, 0, 0, 0, 0};
  for (int it = 0; it < 4; ++it) {
    int d = lane * 16 + it * 4;
    float4 xv = *(const float4*)(xr + d);
    const float* g0 = gW + (size_t)d * 8;
    float xs[4] = {xv.x, xv.y, xv.z, xv.w};
#pragma unroll
    for (int j = 0; j < 4; ++j) {
      const float* gr = g0 + j * 8;
#pragma unroll
      for (int e = 0; e < 8; ++e) a[e] += xs[j] * gr[e];
    }
  }
#pragma unroll
  for (int e = 0; e < 8; ++e)
    for (int off = 32; off; off >>= 1) a[e] += __shfl_xor(a[e], off);
#pragma unroll
  for (int e = 0; e < 8; ++e) a[e] += gb[e];
  float mx = a[0];
#pragma unroll
  for (int e = 1; e < 8; ++e) mx = fmaxf(mx, a[e]);
  float p[8];
  float s = 0.0f;
#pragma unroll
  for (int e = 0; e < 8; ++e) { p[e] = expf(a[e] - mx); s += p[e]; }
  float invs = 1.0f / s;
#pragma unroll
  for (int e = 0; e < 8; ++e) p[e] *= invs;
  int e0 = 0; float p0 = p[0];
#pragma unroll
  for (int e = 1; e < 8; ++e) if (p[e] > p0) { p0 = p[e]; e0 = e; }
  int e1 = -1; float p1 = -1.0f;
#pragma unroll
  for (int e = 0; e < 8; ++e) if (e != e0 && p[e] > p1) { p1 = p[e]; e1 = e; }
  float wsum = p0 + p1;
  if (lane == 0) {
    e0a[n] = e0; e1a[n] = e1;
    w0a[n] = p0 / wsum; w1a[n] = p1 / wsum;
    atomicAdd(&cnt[e0], 1);
    atomicAdd(&cnt[e1], 1);
#pragma unroll
    for (int e = 0; e < 8; ++e) atomicAdd(&Psum[e], p[e]);
  }
}

// ---------------- offsets + tile map + lb ----------------
__global__ void offsets_kernel(const int* __restrict__ cnt, int* __restrict__ offs,
                               int* __restrict__ tile_e, const float* __restrict__ Psum,
                               float* __restrict__ lb)
{
  int off = 0, tl = 0;
  for (int e = 0; e < Ec; ++e) {
    offs[e] = off;
    int nt = (cnt[e] + 127) >> 7;
    for (int i = 0; i < nt; ++i) tile_e[tl++] = e;
    off += nt * 128;
  }
  offs[Ec] = off;
  for (; tl < MAXT; ++tl) tile_e[tl] = -1;
  float s = 0.0f;
  for (int e = 0; e < Ec; ++e)
    s += (cnt[e] * (1.0f / Nc)) * (Psum[e] * (1.0f / Nc));
  lb[0] += (float)Ec * s;
}

// ---------------- scatter tokens into expert segments ----------------
__global__ __launch_bounds__(256) void scatter_kernel(
    const int* __restrict__ e0a, const int* __restrict__ e1a,
    const float* __restrict__ w0a, const float* __restrict__ w1a,
    const int* __restrict__ offs, int* __restrict__ fill,
    int* __restrict__ perm, float* __restrict__ wgt)
{
  int n = blockIdx.x * 256 + threadIdx.x;
  if (n >= Nc) return;
  int e0 = e0a[n], e1 = e1a[n];
  int r0 = atomicAdd(&fill[e0], 1);
  perm[offs[e0] + r0] = n * 2;
  wgt[offs[e0] + r0] = w0a[n];
  int r1 = atomicAdd(&fill[e1], 1);
  perm[offs[e1] + r1] = n * 2 + 1;
  wgt[offs[e1] + r1] = w1a[n];
}

// ---------------- final copy + lb ----------------
__global__ __launch_bounds__(256) void copyout_kernel(
    const float* __restrict__ x, const float* __restrict__ lb, float* __restrict__ out)
{
  size_t i = ((size_t)blockIdx.x * 256 + threadIdx.x) * 4;
  float4 v = *(const float4*)(x + i);
  *(float4*)(out + i) = v;
  if (blockIdx.x == 0 && threadIdx.x == 0) out[(size_t)Nc * Dd] = lb[0];
}

// ---------------- launch ----------------
extern "C" void kernel_launch(void* const* d_in, const int* in_sizes, int n_in,
                              void* d_out, int out_size, void* d_ws, size_t ws_size,
                              hipStream_t stream)
{
  (void)in_sizes; (void)n_in; (void)out_size; (void)ws_size;
  const int*   ids  = (const int*)d_in[0];
  const float* emb  = (const float*)d_in[2];
  const float* pos  = (const float*)d_in[3];
  const float* Wqkv = (const float*)d_in[4];
  const float* bqkv = (const float*)d_in[5];
  const float* Wo   = (const float*)d_in[6];
  const float* bo   = (const float*)d_in[7];
  const float* ln1g = (const float*)d_in[8];
  const float* ln1b = (const float*)d_in[9];
  const float* ln2g = (const float*)d_in[10];
  const float* ln2b = (const float*)d_in[11];
  const float* gW   = (const float*)d_in[12];
  const float* gb   = (const float*)d_in[13];
  const float* W1   = (const float*)d_in[14];
  const float* b1   = (const float*)d_in[15];
  const float* W2   = (const float*)d_in[16];
  const float* b2   = (const float*)d_in[17];
  float* out = (float*)d_out;

  char* w = (char*)d_ws;
  auto alloc = [&](size_t bytes) -> char* {
    char* p = w;
    w += (bytes + 255) & ~(size_t)255;
    return p;
  };
  float* x    = (float*)alloc(sizeof(float) * (size_t)Nc * Dd);
  float* qkv  = (float*)alloc(sizeof(float) * (size_t)Nc * 3 * Dd);
  float* attn = (float*)alloc(sizeof(float) * (size_t)Nc * Dd);
  float* tmp  = (float*)alloc(sizeof(float) * (size_t)Nc * Dd);
  float* moe2 = (float*)alloc(sizeof(float) * (size_t)2 * Nc * Dd);
  float* H    = (float*)alloc(sizeof(float) * (size_t)CAP * HFFc);
  int*   cnt    = (int*)alloc(sizeof(int) * Ec);
  int*   fill   = (int*)alloc(sizeof(int) * Ec);
  int*   offs   = (int*)alloc(sizeof(int) * (Ec + 1));
  int*   tile_e = (int*)alloc(sizeof(int) * MAXT);
  float* Psum   = (float*)alloc(sizeof(float) * Ec);
  float* lb     = (float*)alloc(sizeof(float) * 1);
  int*   e0a    = (int*)alloc(sizeof(int) * Nc);
  int*   e1a    = (int*)alloc(sizeof(int) * Nc);
  float* w0a    = (float*)alloc(sizeof(float) * Nc);
  float* w1a    = (float*)alloc(sizeof(float) * Nc);
  int*   perm   = (int*)alloc(sizeof(int) * CAP);
  float* wgt    = (float*)alloc(sizeof(float) * CAP);

  embed_kernel<<<Nc, 256, 0, stream>>>(ids, emb, pos, x, lb);

  for (int l = 0; l < Lc; ++l) {
    // QKV projection: [8192,1024] @ [1024,3072]
    gemm_kernel<0><<<dim3(Nc / 128, 3 * Dd / 128), 256, 0, stream>>>(
        x, Dd, Wqkv + (size_t)l * Dd * 3 * Dd, 3 * Dd, bqkv + (size_t)l * 3 * Dd,
        qkv, 3 * Dd, Dd, nullptr, 0, 0, nullptr, nullptr, nullptr);

    attn_kernel<<<dim3(Tc / 4, NHc, Bc), 256, 0, stream>>>(qkv, attn);

    // output projection: [8192,1024] @ [1024,1024]
    gemm_kernel<0><<<dim3(Nc / 128, Dd / 128), 256, 0, stream>>>(
        attn, Dd, Wo + (size_t)l * Dd * Dd, Dd, bo + (size_t)l * Dd,
        tmp, Dd, Dd, nullptr, 0, 0, nullptr, nullptr, nullptr);

    ln_kernel<<<Nc, 256, 0, stream>>>(x, tmp, nullptr,
                                      ln1g + (size_t)l * Dd, ln1b + (size_t)l * Dd, x);

    initroute_kernel<<<CAP / 256, 256, 0, stream>>>(perm, cnt, fill, Psum);
    route_kernel<<<Nc, 64, 0, stream>>>(x, gW + (size_t)l * Dd * Ec, gb + (size_t)l * Ec,
                                        e0a, e1a, w0a, w1a, cnt, Psum);
    offsets_kernel<<<1, 1, 0, stream>>>(cnt, offs, tile_e, Psum, lb);
    scatter_kernel<<<Nc / 256, 256, 0, stream>>>(e0a, e1a, w0a, w1a, offs, fill, perm, wgt);

    // expert FF1: gathered [CAP,1024] @ [1024,4096], relu
    gemm_kernel<1><<<dim3(MAXT, HFFc / 128), 256, 0, stream>>>(
        x, Dd, W1 + (size_t)l * Ec * Dd * HFFc, HFFc, b1 + (size_t)l * Ec * HFFc,
        H, HFFc, Dd, tile_e, (long long)Dd * HFFc, HFFc, perm, nullptr, nullptr);

    // expert FF2: [CAP,4096] @ [4096,1024], weighted scatter into moe2 slots
    gemm_kernel<2><<<dim3(MAXT, Dd / 128), 256, 0, stream>>>(
        H, HFFc, W2 + (size_t)l * Ec * HFFc * Dd, Dd, b2 + (size_t)l * Ec * Dd,
        nullptr, 0, HFFc, tile_e, (long long)HFFc * Dd, Dd, perm, wgt, moe2);

    ln_kernel<<<Nc, 256, 0, stream>>>(x, moe2, moe2 + (size_t)Nc * Dd,
                                      ln2g + (size_t)l * Dd, ln2b + (size_t)l * Dd, x);
  }

  copyout_kernel<<<Nc, 256, 0, stream>>>(x, lb, out);
}

// Round 2
// 8081.520 us; speedup vs baseline: 1.6707x; 1.6707x over previous
//
#include <hip/hip_runtime.h>
#include <stdint.h>

// ---------------- problem constants ----------------
constexpr int Dd   = 1024;
constexpr int NHc  = 16;
constexpr int Ec   = 8;
constexpr int Lc   = 2;
constexpr int HFFc = 4096;
constexpr int Bc   = 8;
constexpr int Tc   = 1024;
constexpr int Nc   = Bc * Tc;        // 8192 tokens
constexpr int CAP  = 17408;          // padded token-expert rows capacity
constexpr int MAXT = CAP / 128;      // 136 M-tiles for MoE GEMMs

typedef _Float16 half8  __attribute__((ext_vector_type(8)));
typedef _Float16 half4v __attribute__((ext_vector_type(4)));
typedef _Float16 half2v __attribute__((ext_vector_type(2)));
typedef float    f32x4  __attribute__((ext_vector_type(4)));

// split: x = hi + lo/2048, both fp16 normal-range
// ---------------- embed (+ split planes) ----------------
__global__ __launch_bounds__(256) void embed_kernel(
    const int* __restrict__ ids, const float* __restrict__ emb,
    const float* __restrict__ pos, float* __restrict__ x,
    _Float16* __restrict__ xh, _Float16* __restrict__ xl, float* __restrict__ lb)
{
  int n = blockIdx.x;
  int tid = threadIdx.x;
  int id = ids[n];
  int tpos = n & (Tc - 1);
  size_t o = (size_t)n * Dd + tid * 4;
  float4 e = *(const float4*)(emb + (size_t)id * Dd + tid * 4);
  float4 p = *(const float4*)(pos + (size_t)tpos * Dd + tid * 4);
  float4 r;
  r.x = e.x + p.x; r.y = e.y + p.y; r.z = e.z + p.z; r.w = e.w + p.w;
  *(float4*)(x + o) = r;
  _Float16 h0=(_Float16)r.x, h1=(_Float16)r.y, h2=(_Float16)r.z, h3=(_Float16)r.w;
  _Float16 l0=(_Float16)((r.x-(float)h0)*2048.0f);
  _Float16 l1=(_Float16)((r.y-(float)h1)*2048.0f);
  _Float16 l2=(_Float16)((r.z-(float)h2)*2048.0f);
  _Float16 l3=(_Float16)((r.w-(float)h3)*2048.0f);
  half4v hh = {h0,h1,h2,h3};
  half4v llv = {l0,l1,l2,l3};
  *(half4v*)(xh + o) = hh;
  *(half4v*)(xl + o) = llv;
  if (n == 0 && tid == 0) lb[0] = 0.0f;
}

// ---------------- weight convert: [K][N] fp32 -> [N][K] fp16 hi/lo planes ----------------
__global__ __launch_bounds__(256) void convw_kernel(
    const float* __restrict__ src, _Float16* __restrict__ dh,
    _Float16* __restrict__ dl, int K, int N, int write_lo)
{
  int b = blockIdx.z;
  src += (size_t)b * K * N;
  dh  += (size_t)b * K * N;
  dl  += (size_t)b * K * N;
  int n0 = blockIdx.x * 64, k0 = blockIdx.y * 64;
  int t = threadIdx.x;
  __shared__ float T[64][65];
#pragma unroll
  for (int i = 0; i < 16; ++i) {
    int kk = (t >> 6) + i * 4, nn = t & 63;
    T[kk][nn] = src[(size_t)(k0 + kk) * N + n0 + nn];
  }
  __syncthreads();
#pragma unroll
  for (int i = 0; i < 8; ++i) {
    int nn = (t >> 5) + i * 8, kk = (t & 31) * 2;
    float w0 = T[kk][nn], w1 = T[kk + 1][nn];
    _Float16 h0 = (_Float16)w0, h1 = (_Float16)w1;
    size_t base = (size_t)(n0 + nn) * K + k0 + kk;
    half2v hv = {h0, h1};
    *(half2v*)(dh + base) = hv;
    if (write_lo) {
      _Float16 u0 = (_Float16)((w0 - (float)h0) * 2048.0f);
      _Float16 u1 = (_Float16)((w1 - (float)h1) * 2048.0f);
      half2v lv = {u0, u1};
      *(half2v*)(dl + base) = lv;
    }
  }
}

// ---------------- split-fp16 MFMA GEMM, 128x128x32, 256 threads ----------------
// A planes [m][k] (hi, lo*2048), B planes [n][k]. result = acc0 + acc1/2048.
// MODE 0: C = A@B + bias (fp32 out)
// MODE 1: H planes = split(relu(A@B + bias[e])), A rows gathered via perm
// MODE 2: moe_out[slot][tok] = wgt*(A@B + bias[e])
template<int MODE, int PASSES>
__global__ __launch_bounds__(256)
void mgemm(const _Float16* __restrict__ Ah, const _Float16* __restrict__ Al, int lda,
           const _Float16* __restrict__ Bh, const _Float16* __restrict__ Bl,
           const float* __restrict__ bias,
           float* __restrict__ C, int ldc,
           _Float16* __restrict__ Oh, _Float16* __restrict__ Ol, int ldo,
           int K,
           const int* __restrict__ tile_e, long long strideB, int strideBias,
           const int* __restrict__ perm, const float* __restrict__ wgt,
           float* __restrict__ moe_out)
{
  __shared__ _Float16 sAh[128 * 40];
  __shared__ _Float16 sBh[128 * 40];
  __shared__ _Float16 sAl[(PASSES == 3) ? 128 * 40 : 8];
  __shared__ _Float16 sBl[(PASSES == 3) ? 128 * 40 : 8];

  const int tid = threadIdx.x;
  const int m0 = blockIdx.x * 128;
  const int n0 = blockIdx.y * 128;
  const _Float16* bh = Bh;
  const _Float16* bl = Bl;
  const float* bp = bias;
  if (MODE != 0) {
    int e = tile_e[blockIdx.x];
    if (e < 0) return;
    bh += (size_t)e * (size_t)strideB;
    bl += (size_t)e * (size_t)strideB;
    bp += (size_t)e * strideBias;
  }

  const int srow = tid >> 1;
  const int skb  = (tid & 1) * 16;
  size_t aoff;
  if (MODE == 1) {
    int pp = perm[m0 + srow];
    int tok = (pp < 0) ? 0 : (pp >> 1);
    aoff = (size_t)tok * lda + skb;
  } else {
    aoff = (size_t)(m0 + srow) * lda + skb;
  }
  const size_t boff = (size_t)(n0 + srow) * K + skb;

  const int lane = tid & 63, wv = tid >> 6;
  const int wm = (wv & 1) * 64, wn = (wv >> 1) * 64;
  const int fr = lane & 15, quad = lane >> 4;

  f32x4 acc0[16];
  f32x4 acc1[16];
#pragma unroll
  for (int i = 0; i < 16; ++i) {
    acc0[i][0]=0.f; acc0[i][1]=0.f; acc0[i][2]=0.f; acc0[i][3]=0.f;
    if (PASSES == 3) { acc1[i][0]=0.f; acc1[i][1]=0.f; acc1[i][2]=0.f; acc1[i][3]=0.f; }
  }

  const int lidx = srow * 40 + skb;
  for (int k0 = 0; k0 < K; k0 += 32) {
    {
      const _Float16* s = Ah + aoff + k0;
      float4 v0 = *(const float4*)s;
      float4 v1 = *(const float4*)(s + 8);
      *(float4*)&sAh[lidx] = v0; *(float4*)&sAh[lidx + 8] = v1;
    }
    {
      const _Float16* s = bh + boff + k0;
      float4 v0 = *(const float4*)s;
      float4 v1 = *(const float4*)(s + 8);
      *(float4*)&sBh[lidx] = v0; *(float4*)&sBh[lidx + 8] = v1;
    }
    if (PASSES == 3) {
      {
        const _Float16* s = Al + aoff + k0;
        float4 v0 = *(const float4*)s;
        float4 v1 = *(const float4*)(s + 8);
        *(float4*)&sAl[lidx] = v0; *(float4*)&sAl[lidx + 8] = v1;
      }
      {
        const _Float16* s = bl + boff + k0;
        float4 v0 = *(const float4*)s;
        float4 v1 = *(const float4*)(s + 8);
        *(float4*)&sBl[lidx] = v0; *(float4*)&sBl[lidx + 8] = v1;
      }
    }
    __syncthreads();

    half8 fa[4], fb[4], ga[4], gb[4];
#pragma unroll
    for (int i = 0; i < 4; ++i) {
      int ar = (wm + i * 16 + fr) * 40 + quad * 8;
      int br = (wn + i * 16 + fr) * 40 + quad * 8;
      fa[i] = *(const half8*)&sAh[ar];
      fb[i] = *(const half8*)&sBh[br];
      if (PASSES == 3) {
        ga[i] = *(const half8*)&sAl[ar];
        gb[i] = *(const half8*)&sBl[br];
      }
    }
#pragma unroll
    for (int mi = 0; mi < 4; ++mi)
#pragma unroll
      for (int ni = 0; ni < 4; ++ni) {
        acc0[mi * 4 + ni] = __builtin_amdgcn_mfma_f32_16x16x32_f16(fa[mi], fb[ni], acc0[mi * 4 + ni], 0, 0, 0);
        if (PASSES == 3) {
          acc1[mi * 4 + ni] = __builtin_amdgcn_mfma_f32_16x16x32_f16(fa[mi], gb[ni], acc1[mi * 4 + ni], 0, 0, 0);
          acc1[mi * 4 + ni] = __builtin_amdgcn_mfma_f32_16x16x32_f16(ga[mi], fb[ni], acc1[mi * 4 + ni], 0, 0, 0);
        }
      }
    __syncthreads();
  }

  // epilogue: C/D layout col=lane&15, row=quad*4+reg
  const float ls = 1.0f / 2048.0f;
#pragma unroll
  for (int mi = 0; mi < 4; ++mi) {
#pragma unroll
    for (int ni = 0; ni < 4; ++ni) {
      f32x4 v = acc0[mi * 4 + ni];
      if (PASSES == 3) {
        f32x4 u = acc1[mi * 4 + ni];
        v[0] += u[0] * ls; v[1] += u[1] * ls; v[2] += u[2] * ls; v[3] += u[3] * ls;
      }
      int gcol = n0 + wn + ni * 16 + fr;
      float bv = bp[gcol];
#pragma unroll
      for (int r = 0; r < 4; ++r) {
        int grow = m0 + wm + mi * 16 + quad * 4 + r;
        float val = v[r] + bv;
        if (MODE == 0) {
          C[(size_t)grow * ldc + gcol] = val;
        } else if (MODE == 1) {
          val = fmaxf(val, 0.0f);
          _Float16 hv = (_Float16)val;
          Oh[(size_t)grow * ldo + gcol] = hv;
          if (PASSES == 3)
            Ol[(size_t)grow * ldo + gcol] = (_Float16)((val - (float)hv) * 2048.0f);
        } else {
          int pp = perm[grow];
          if (pp >= 0) {
            float wvv = wgt[grow];
            int tok = pp >> 1, slot = pp & 1;
            moe_out[((size_t)slot * Nc + tok) * Dd + gcol] = val * wvv;
          }
        }
      }
    }
  }
}

// ---------------- causal attention: 4 query rows / block ----------------
__global__ __launch_bounds__(256) void attn_kernel(
    const float* __restrict__ qkv, _Float16* __restrict__ oh, _Float16* __restrict__ ol)
{
  int t0 = blockIdx.x * 4;
  int h = blockIdx.y;
  int b = blockIdx.z;
  int tid = threadIdx.x;
  int wave = tid >> 6, lane = tid & 63;
  int t = t0 + wave;

  __shared__ float Kl[64][65];
  __shared__ float Sl[4][1024];
  __shared__ float ql[4][64];

  {
    int w = tid >> 6;
    int d = tid & 63;
    ql[w][d] = qkv[((size_t)(b * Tc + t0 + w)) * 3072 + (h << 6) + d] * 0.125f;
  }
  __syncthreads();

  float qreg[64];
#pragma unroll
  for (int d = 0; d < 64; ++d) qreg[d] = ql[wave][d];

  int nch = (t0 + 3) / 64 + 1;

  for (int c = 0; c < nch; ++c) {
    int s0 = c * 64;
    {
      int r = tid >> 2, db = (tid & 3) * 16;
      const float* src = qkv + ((size_t)(b * Tc + s0 + r)) * 3072 + Dd + (h << 6) + db;
#pragma unroll
      for (int cc = 0; cc < 4; ++cc) {
        float4 v = *(const float4*)(src + 4 * cc);
        Kl[r][db + 4 * cc + 0] = v.x; Kl[r][db + 4 * cc + 1] = v.y;
        Kl[r][db + 4 * cc + 2] = v.z; Kl[r][db + 4 * cc + 3] = v.w;
      }
    }
    __syncthreads();
    {
      int s = s0 + lane;
      float sc = -1e30f;
      if (s <= t) {
        float a = 0.0f;
#pragma unroll
        for (int d = 0; d < 64; ++d) a += qreg[d] * Kl[lane][d];
        sc = a;
      }
      Sl[wave][s] = sc;
    }
    __syncthreads();
  }

  float m = -1e30f;
  for (int s = lane; s < nch * 64; s += 64) m = fmaxf(m, Sl[wave][s]);
  for (int off = 32; off; off >>= 1) m = fmaxf(m, __shfl_xor(m, off));
  float sum = 0.0f;
  for (int s = lane; s < nch * 64; s += 64) {
    float p = expf(Sl[wave][s] - m);
    Sl[wave][s] = p;
    sum += p;
  }
  for (int off = 32; off; off >>= 1) sum += __shfl_xor(sum, off);
  float inv = 1.0f / sum;
  __syncthreads();

  float o = 0.0f;
  for (int c = 0; c < nch; ++c) {
    int s0 = c * 64;
    {
      int r = tid >> 2, db = (tid & 3) * 16;
      const float* src = qkv + ((size_t)(b * Tc + s0 + r)) * 3072 + 2 * Dd + (h << 6) + db;
#pragma unroll
      for (int cc = 0; cc < 4; ++cc) {
        float4 v = *(const float4*)(src + 4 * cc);
        Kl[r][db + 4 * cc + 0] = v.x; Kl[r][db + 4 * cc + 1] = v.y;
        Kl[r][db + 4 * cc + 2] = v.z; Kl[r][db + 4 * cc + 3] = v.w;
      }
    }
    __syncthreads();
    int lim = t - s0 + 1;
    if (lim > 64) lim = 64;
    if (lim < 0) lim = 0;
    for (int i = 0; i < lim; ++i) o += Sl[wave][s0 + i] * Kl[i][lane];
    __syncthreads();
  }
  float ov = o * inv;
  _Float16 hv = (_Float16)ov;
  _Float16 lv = (_Float16)((ov - (float)hv) * 2048.0f);
  size_t oo = ((size_t)(b * Tc + t)) * Dd + (h << 6) + lane;
  oh[oo] = hv;
  ol[oo] = lv;
}

// ---------------- LayerNorm (x + add1 [+ add2]) + split planes ----------------
__global__ __launch_bounds__(256) void ln_kernel(
    const float* __restrict__ xin, const float* __restrict__ add1,
    const float* __restrict__ add2, const float* __restrict__ g,
    const float* __restrict__ bt, float* __restrict__ xout,
    _Float16* __restrict__ xh, _Float16* __restrict__ xl)
{
  int row = blockIdx.x;
  int tid = threadIdx.x;
  size_t base = (size_t)row * Dd + tid * 4;
  float4 v = *(const float4*)(xin + base);
  float4 a = *(const float4*)(add1 + base);
  v.x += a.x; v.y += a.y; v.z += a.z; v.w += a.w;
  if (add2) {
    float4 a2 = *(const float4*)(add2 + base);
    v.x += a2.x; v.y += a2.y; v.z += a2.z; v.w += a2.w;
  }
  float s = v.x + v.y + v.z + v.w;
  float q = v.x * v.x + v.y * v.y + v.z * v.z + v.w * v.w;
  for (int off = 32; off; off >>= 1) {
    s += __shfl_xor(s, off);
    q += __shfl_xor(q, off);
  }
  __shared__ float red[4][2];
  int wave = tid >> 6, lane = tid & 63;
  if (lane == 0) { red[wave][0] = s; red[wave][1] = q; }
  __syncthreads();
  s = red[0][0] + red[1][0] + red[2][0] + red[3][0];
  q = red[0][1] + red[1][1] + red[2][1] + red[3][1];
  float mean = s * (1.0f / Dd);
  float var = q * (1.0f / Dd) - mean * mean;
  float rsig = 1.0f / sqrtf(var + 1e-5f);
  float4 gg = *(const float4*)(g + tid * 4);
  float4 bb = *(const float4*)(bt + tid * 4);
  float4 ov;
  ov.x = (v.x - mean) * rsig * gg.x + bb.x;
  ov.y = (v.y - mean) * rsig * gg.y + bb.y;
  ov.z = (v.z - mean) * rsig * gg.z + bb.z;
  ov.w = (v.w - mean) * rsig * gg.w + bb.w;
  *(float4*)(xout + base) = ov;
  _Float16 h0=(_Float16)ov.x, h1=(_Float16)ov.y, h2=(_Float16)ov.z, h3=(_Float16)ov.w;
  _Float16 l0=(_Float16)((ov.x-(float)h0)*2048.0f);
  _Float16 l1=(_Float16)((ov.y-(float)h1)*2048.0f);
  _Float16 l2=(_Float16)((ov.z-(float)h2)*2048.0f);
  _Float16 l3=(_Float16)((ov.w-(float)h3)*2048.0f);
  half4v hh = {h0,h1,h2,h3};
  half4v llv = {l0,l1,l2,l3};
  *(half4v*)(xh + base) = hh;
  *(half4v*)(xl + base) = llv;
}

// ---------------- routing init ----------------
__global__ __launch_bounds__(256) void initroute_kernel(
    int* __restrict__ perm, int* __restrict__ cnt, int* __restrict__ fill,
    float* __restrict__ Psum)
{
  int i = blockIdx.x * 256 + threadIdx.x;
  if (i < CAP) perm[i] = -1;
  if (blockIdx.x == 0 && threadIdx.x < Ec) {
    cnt[threadIdx.x] = 0;
    fill[threadIdx.x] = 0;
    Psum[threadIdx.x] = 0.0f;
  }
}

// ---------------- router: one wave per token (fp32 exact) ----------------
__global__ __launch_bounds__(64) void route_kernel(
    const float* __restrict__ x, const float* __restrict__ gW,
    const float* __restrict__ gb,
    int* __restrict__ e0a, int* __restrict__ e1a,
    float* __restrict__ w0a, float* __restrict__ w1a,
    int* __restrict__ cnt, float* __restrict__ Psum)
{
  int n = blockIdx.x;
  int lane = threadIdx.x;
  const float* xr = x + (size_t)n * Dd;
  float a[8] = {0, 0, 0, 0, 0, 0, 0, 0};
  for (int it = 0; it < 4; ++it) {
    int d = lane * 16 + it * 4;
    float4 xv = *(const float4*)(xr + d);
    const float* g0 = gW + (size_t)d * 8;
    float xs[4] = {xv.x, xv.y, xv.z, xv.w};
#pragma unroll
    for (int j = 0; j < 4; ++j) {
      const float* gr = g0 + j * 8;
#pragma unroll
      for (int e = 0; e < 8; ++e) a[e] += xs[j] * gr[e];
    }
  }
#pragma unroll
  for (int e = 0; e < 8; ++e)
    for (int off = 32; off; off >>= 1) a[e] += __shfl_xor(a[e], off);
#pragma unroll
  for (int e = 0; e < 8; ++e) a[e] += gb[e];
  float mx = a[0];
#pragma unroll
  for (int e = 1; e < 8; ++e) mx = fmaxf(mx, a[e]);
  float p[8];
  float s = 0.0f;
#pragma unroll
  for (int e = 0; e < 8; ++e) { p[e] = expf(a[e] - mx); s += p[e]; }
  float invs = 1.0f / s;
#pragma unroll
  for (int e = 0; e < 8; ++e) p[e] *= invs;
  int e0 = 0; float p0 = p[0];
#pragma unroll
  for (int e = 1; e < 8; ++e) if (p[e] > p0) { p0 = p[e]; e0 = e; }
  int e1 = -1; float p1 = -1.0f;
#pragma unroll
  for (int e = 0; e < 8; ++e) if (e != e0 && p[e] > p1) { p1 = p[e]; e1 = e; }
  float wsum = p0 + p1;
  if (lane == 0) {
    e0a[n] = e0; e1a[n] = e1;
    w0a[n] = p0 / wsum; w1a[n] = p1 / wsum;
    atomicAdd(&cnt[e0], 1);
    atomicAdd(&cnt[e1], 1);
#pragma unroll
    for (int e = 0; e < 8; ++e) atomicAdd(&Psum[e], p[e]);
  }
}

// ---------------- offsets + tile map + lb ----------------
__global__ void offsets_kernel(const int* __restrict__ cnt, int* __restrict__ offs,
                               int* __restrict__ tile_e, const float* __restrict__ Psum,
                               float* __restrict__ lb)
{
  int off = 0, tl = 0;
  for (int e = 0; e < Ec; ++e) {
    offs[e] = off;
    int nt = (cnt[e] + 127) >> 7;
    for (int i = 0; i < nt; ++i) tile_e[tl++] = e;
    off += nt * 128;
  }
  offs[Ec] = off;
  for (; tl < MAXT; ++tl) tile_e[tl] = -1;
  float s = 0.0f;
  for (int e = 0; e < Ec; ++e)
    s += (cnt[e] * (1.0f / Nc)) * (Psum[e] * (1.0f / Nc));
  lb[0] += (float)Ec * s;
}

// ---------------- scatter tokens into expert segments ----------------
__global__ __launch_bounds__(256) void scatter_kernel(
    const int* __restrict__ e0a, const int* __restrict__ e1a,
    const float* __restrict__ w0a, const float* __restrict__ w1a,
    const int* __restrict__ offs, int* __restrict__ fill,
    int* __restrict__ perm, float* __restrict__ wgt)
{
  int n = blockIdx.x * 256 + threadIdx.x;
  if (n >= Nc) return;
  int e0 = e0a[n], e1 = e1a[n];
  int r0 = atomicAdd(&fill[e0], 1);
  perm[offs[e0] + r0] = n * 2;
  wgt[offs[e0] + r0] = w0a[n];
  int r1 = atomicAdd(&fill[e1], 1);
  perm[offs[e1] + r1] = n * 2 + 1;
  wgt[offs[e1] + r1] = w1a[n];
}

// ---------------- final copy + lb ----------------
__global__ __launch_bounds__(256) void copyout_kernel(
    const float* __restrict__ x, const float* __restrict__ lb, float* __restrict__ out)
{
  size_t i = ((size_t)blockIdx.x * 256 + threadIdx.x) * 4;
  float4 v = *(const float4*)(x + i);
  *(float4*)(out + i) = v;
  if (blockIdx.x == 0 && threadIdx.x == 0) out[(size_t)Nc * Dd] = lb[0];
}

// ---------------- launch ----------------
extern "C" void kernel_launch(void* const* d_in, const int* in_sizes, int n_in,
                              void* d_out, int out_size, void* d_ws, size_t ws_size,
                              hipStream_t stream)
{
  (void)in_sizes; (void)n_in; (void)out_size; (void)ws_size;
  const int*   ids  = (const int*)d_in[0];
  const float* emb  = (const float*)d_in[2];
  const float* pos  = (const float*)d_in[3];
  const float* Wqkv = (const float*)d_in[4];
  const float* bqkv = (const float*)d_in[5];
  const float* Wo   = (const float*)d_in[6];
  const float* bo   = (const float*)d_in[7];
  const float* ln1g = (const float*)d_in[8];
  const float* ln1b = (const float*)d_in[9];
  const float* ln2g = (const float*)d_in[10];
  const float* ln2b = (const float*)d_in[11];
  const float* gW   = (const float*)d_in[12];
  const float* gb   = (const float*)d_in[13];
  const float* W1   = (const float*)d_in[14];
  const float* b1   = (const float*)d_in[15];
  const float* W2   = (const float*)d_in[16];
  const float* b2   = (const float*)d_in[17];
  float* out = (float*)d_out;

  char* w = (char*)d_ws;
  auto alloc = [&](size_t bytes) -> char* {
    char* p = w;
    w += (bytes + 255) & ~(size_t)255;
    return p;
  };
  float*     x    = (float*)alloc(sizeof(float) * (size_t)Nc * Dd);
  _Float16*  xh   = (_Float16*)alloc(2ull * Nc * Dd);
  _Float16*  xl   = (_Float16*)alloc(2ull * Nc * Dd);
  float*     qkv  = (float*)alloc(sizeof(float) * (size_t)Nc * 3 * Dd);
  _Float16*  ash  = (_Float16*)alloc(2ull * Nc * Dd);
  _Float16*  asl  = (_Float16*)alloc(2ull * Nc * Dd);
  float*     tmp  = (float*)alloc(sizeof(float) * (size_t)Nc * Dd);
  float*     moe2 = (float*)alloc(sizeof(float) * (size_t)2 * Nc * Dd);
  _Float16*  Hh   = (_Float16*)alloc(2ull * CAP * HFFc);
  _Float16*  Hl   = (_Float16*)alloc(2ull * CAP * HFFc);
  _Float16*  WqkvTh = (_Float16*)alloc(2ull * Lc * 3 * Dd * Dd);
  _Float16*  WqkvTl = (_Float16*)alloc(2ull * Lc * 3 * Dd * Dd);
  _Float16*  WoTh   = (_Float16*)alloc(2ull * Lc * Dd * Dd);
  _Float16*  WoTl   = (_Float16*)alloc(2ull * Lc * Dd * Dd);
  _Float16*  W1Th   = (_Float16*)alloc(2ull * Ec * Dd * HFFc);
  _Float16*  W1Tl   = (_Float16*)alloc(2ull * Ec * Dd * HFFc);
  _Float16*  W2Th   = (_Float16*)alloc(2ull * Ec * HFFc * Dd);
  _Float16*  W2Tl   = (_Float16*)alloc(2ull * Ec * HFFc * Dd);
  int*   cnt    = (int*)alloc(sizeof(int) * Ec);
  int*   fill   = (int*)alloc(sizeof(int) * Ec);
  int*   offs   = (int*)alloc(sizeof(int) * (Ec + 1));
  int*   tile_e = (int*)alloc(sizeof(int) * MAXT);
  float* Psum   = (float*)alloc(sizeof(float) * Ec);
  float* lb     = (float*)alloc(sizeof(float) * 1);
  int*   e0a    = (int*)alloc(sizeof(int) * Nc);
  int*   e1a    = (int*)alloc(sizeof(int) * Nc);
  float* w0a    = (float*)alloc(sizeof(float) * Nc);
  float* w1a    = (float*)alloc(sizeof(float) * Nc);
  int*   perm   = (int*)alloc(sizeof(int) * CAP);
  float* wgt    = (float*)alloc(sizeof(float) * CAP);

  embed_kernel<<<Nc, 256, 0, stream>>>(ids, emb, pos, x, xh, xl, lb);

  // convert Wqkv, Wo (both layers) to transposed split planes
  convw_kernel<<<dim3(3 * Dd / 64, Dd / 64, Lc), 256, 0, stream>>>(
      Wqkv, WqkvTh, WqkvTl, Dd, 3 * Dd, 1);
  convw_kernel<<<dim3(Dd / 64, Dd / 64, Lc), 256, 0, stream>>>(
      Wo, WoTh, WoTl, Dd, Dd, 1);

  for (int l = 0; l < Lc; ++l) {
    // QKV projection (3-pass): [8192,1024]@[1024,3072]
    mgemm<0, 3><<<dim3(Nc / 128, 3 * Dd / 128), 256, 0, stream>>>(
        xh, xl, Dd,
        WqkvTh + (size_t)l * 3 * Dd * Dd, WqkvTl + (size_t)l * 3 * Dd * Dd,
        bqkv + (size_t)l * 3 * Dd,
        qkv, 3 * Dd, nullptr, nullptr, 0, Dd,
        nullptr, 0, 0, nullptr, nullptr, nullptr);

    attn_kernel<<<dim3(Tc / 4, NHc, Bc), 256, 0, stream>>>(qkv, ash, asl);

    // output projection (3-pass): [8192,1024]@[1024,1024]
    mgemm<0, 3><<<dim3(Nc / 128, Dd / 128), 256, 0, stream>>>(
        ash, asl, Dd,
        WoTh + (size_t)l * Dd * Dd, WoTl + (size_t)l * Dd * Dd,
        bo + (size_t)l * Dd,
        tmp, Dd, nullptr, nullptr, 0, Dd,
        nullptr, 0, 0, nullptr, nullptr, nullptr);

    ln_kernel<<<Nc, 256, 0, stream>>>(x, tmp, nullptr,
                                      ln1g + (size_t)l * Dd, ln1b + (size_t)l * Dd,
                                      x, xh, xl);

    initroute_kernel<<<CAP / 256, 256, 0, stream>>>(perm, cnt, fill, Psum);
    route_kernel<<<Nc, 64, 0, stream>>>(x, gW + (size_t)l * Dd * Ec, gb + (size_t)l * Ec,
                                        e0a, e1a, w0a, w1a, cnt, Psum);
    offsets_kernel<<<1, 1, 0, stream>>>(cnt, offs, tile_e, Psum, lb);
    scatter_kernel<<<Nc / 256, 256, 0, stream>>>(e0a, e1a, w0a, w1a, offs, fill, perm, wgt);

    // convert this layer's expert weights
    convw_kernel<<<dim3(HFFc / 64, Dd / 64, Ec), 256, 0, stream>>>(
        W1 + (size_t)l * Ec * Dd * HFFc, W1Th, W1Tl, Dd, HFFc, (l == 0) ? 1 : 0);
    convw_kernel<<<dim3(Dd / 64, HFFc / 64, Ec), 256, 0, stream>>>(
        W2 + (size_t)l * Ec * HFFc * Dd, W2Th, W2Tl, HFFc, Dd, (l == 0) ? 1 : 0);

    // FF1: gathered [CAP,1024]@[1024,4096], relu -> H planes
    if (l == 0)
      mgemm<1, 3><<<dim3(MAXT, HFFc / 128), 256, 0, stream>>>(
          xh, xl, Dd, W1Th, W1Tl, b1 + (size_t)l * Ec * HFFc,
          nullptr, 0, Hh, Hl, HFFc, Dd,
          tile_e, (long long)Dd * HFFc, HFFc, perm, nullptr, nullptr);
    else
      mgemm<1, 1><<<dim3(MAXT, HFFc / 128), 256, 0, stream>>>(
          xh, xl, Dd, W1Th, W1Tl, b1 + (size_t)l * Ec * HFFc,
          nullptr, 0, Hh, Hl, HFFc, Dd,
          tile_e, (long long)Dd * HFFc, HFFc, perm, nullptr, nullptr);

    // FF2: [CAP,4096]@[4096,1024], weighted scatter into moe2 slots
    if (l == 0)
      mgemm<2, 3><<<dim3(MAXT, Dd / 128), 256, 0, stream>>>(
          Hh, Hl, HFFc, W2Th, W2Tl, b2 + (size_t)l * Ec * Dd,
          nullptr, 0, nullptr, nullptr, 0, HFFc,
          tile_e, (long long)HFFc * Dd, Dd, perm, wgt, moe2);
    else
      mgemm<2, 1><<<dim3(MAXT, Dd / 128), 256, 0, stream>>>(
          Hh, Hl, HFFc, W2Th, W2Tl, b2 + (size_t)l * Ec * Dd,
          nullptr, 0, nullptr, nullptr, 0, HFFc,
          tile_e, (long long)HFFc * Dd, Dd, perm, wgt, moe2);

    ln_kernel<<<Nc, 256, 0, stream>>>(x, moe2, moe2 + (size_t)Nc * Dd,
                                      ln2g + (size_t)l * Dd, ln2b + (size_t)l * Dd,
                                      x, xh, xl);
  }

  copyout_kernel<<<Nc, 256, 0, stream>>>(x, lb, out);
}